// Round 3
// baseline (112.424 us; speedup 1.0000x reference)
//
#include <hip/hip_runtime.h>

// TSClusteringLayer: q[n,k] = studentT(sum_f sqrt(sum_t (x[n,t,f]-c[k,t,f])^2)), row-normalized.
// x: (2048,128,32) f32, clusters: (32,128,32) f32, out: (2048,32) f32.
//
// v3: v2 compute structure + PRE-TRANSPOSED clusters.
//   Theory: v1/v2 stall (all pipes idle) is the k-strided c-gather
//   (8 segments x 64KB apart per load instruction). Transpose clusters once
//   to c2[t][k][f] (512 KB in d_ws) so every c-load is lane-contiguous 1KB.
//
//   Main kernel: 512 blocks x 512 threads (8 waves). Block covers NB=4 n.
//   Wave w (0..7) handles t-range [w*16, w*16+16) for ALL 4 n.
//   Lane: f_grp=lane&7 (f0=4*f_grp), k_grp=(lane>>3)&7 (k0=4*k_grp).
//   Thread tile: 4n x 4k x 4f -> 64 fp32 accumulators.
//   Cross-wave combine: 2-round LDS tree (stride-65 -> conflict-free).

#define T_DIM 128
#define F_DIM 32
#define K_DIM 32
#define TF (T_DIM * F_DIM)
#define KF (K_DIM * F_DIM)   // 1024: row size of c2 per t
#define NB 4
#define TS 8
#define TT (T_DIM/TS)
#define SLOT_STRIDE 65

// c2[t*1024 + k*32 + f] = c[k*4096 + t*32 + f]
__global__ __launch_bounds__(256) void transpose_c_kernel(
    const float* __restrict__ c, float* __restrict__ c2)
{
    const int idx = blockIdx.x * 256 + threadIdx.x;   // 131072 total
    const int t  = idx >> 10;
    const int kf = idx & 1023;
    const int k  = kf >> 5;
    const int f  = kf & 31;
    c2[idx] = c[k * TF + t * F_DIM + f];
}

__global__ __launch_bounds__(512, 4) void tscluster_kernel(
    const float* __restrict__ x,
    const float* __restrict__ c2,
    float* __restrict__ out)
{
    __shared__ float lds[4 * 64 * SLOT_STRIDE]; // 66560 B

    const int tid   = threadIdx.x;
    const int lane  = tid & 63;
    const int w     = tid >> 6;        // t-split index 0..7
    const int f_grp = lane & 7;
    const int k_grp = (lane >> 3) & 7;
    const int f0 = f_grp << 2;
    const int k0 = k_grp << 2;
    const int n0 = blockIdx.x * NB;

    const float* xp = x + (size_t)n0 * TF + w * TT * F_DIM + f0;
    const float* cp = c2 + (size_t)(w * TT) * KF + k0 * F_DIM /*k stride in c2 is 32*/ + f0;
    // NOTE: in c2, element (t,k,f) is at t*KF + k*32 + f. k0*F_DIM is WRONG; fix below.

    float acc[NB][4][4];
    #pragma unroll
    for (int a = 0; a < NB; ++a)
        #pragma unroll
        for (int b = 0; b < 4; ++b)
            #pragma unroll
            for (int j = 0; j < 4; ++j)
                acc[a][b][j] = 0.0f;

    const float* cpp = c2 + (size_t)(w * TT) * KF + k0 * 32 + f0;

    #pragma unroll 2
    for (int tt = 0; tt < TT; ++tt) {
        const int xoff = tt * F_DIM;
        const int coff = tt * KF;

        float4 xv[NB], cv[4];
        #pragma unroll
        for (int a = 0; a < NB; ++a)
            xv[a] = *reinterpret_cast<const float4*>(xp + (size_t)a * TF + xoff);
        #pragma unroll
        for (int b = 0; b < 4; ++b)
            cv[b] = *reinterpret_cast<const float4*>(cpp + coff + b * 32);

        float xs[NB][4], cs[4][4];
        #pragma unroll
        for (int a = 0; a < NB; ++a) {
            xs[a][0] = xv[a].x; xs[a][1] = xv[a].y; xs[a][2] = xv[a].z; xs[a][3] = xv[a].w;
        }
        #pragma unroll
        for (int b = 0; b < 4; ++b) {
            cs[b][0] = cv[b].x; cs[b][1] = cv[b].y; cs[b][2] = cv[b].z; cs[b][3] = cv[b].w;
        }

        #pragma unroll
        for (int a = 0; a < NB; ++a)
            #pragma unroll
            for (int b = 0; b < 4; ++b)
                #pragma unroll
                for (int j = 0; j < 4; ++j) {
                    const float d = xs[a][j] - cs[b][j];
                    acc[a][b][j] += d * d;
                }
    }

    // ---- combine partial accs across the 8 waves (tree via LDS) ----
    float* accf = &acc[0][0][0];

    if (w >= 4) {
        float* dst = lds + ((size_t)(w - 4) * 64 + lane) * SLOT_STRIDE;
        #pragma unroll
        for (int i = 0; i < 64; ++i) dst[i] = accf[i];
    }
    __syncthreads();
    if (w < 4) {
        const float* src = lds + ((size_t)w * 64 + lane) * SLOT_STRIDE;
        #pragma unroll
        for (int i = 0; i < 64; ++i) accf[i] += src[i];
    }
    __syncthreads();
    if (w >= 1 && w < 4) {
        float* dst = lds + ((size_t)(w - 1) * 64 + lane) * SLOT_STRIDE;
        #pragma unroll
        for (int i = 0; i < 64; ++i) dst[i] = accf[i];
    }
    __syncthreads();

    if (w == 0) {
        #pragma unroll
        for (int s = 0; s < 3; ++s) {
            const float* src = lds + ((size_t)s * 64 + lane) * SLOT_STRIDE;
            #pragma unroll
            for (int i = 0; i < 64; ++i) accf[i] += src[i];
        }

        float dist[NB][4];
        #pragma unroll
        for (int a = 0; a < NB; ++a)
            #pragma unroll
            for (int b = 0; b < 4; ++b)
                dist[a][b] = sqrtf(acc[a][b][0]) + sqrtf(acc[a][b][1]) +
                             sqrtf(acc[a][b][2]) + sqrtf(acc[a][b][3]);

        #pragma unroll
        for (int off = 1; off < 8; off <<= 1)
            #pragma unroll
            for (int a = 0; a < NB; ++a)
                #pragma unroll
                for (int b = 0; b < 4; ++b)
                    dist[a][b] += __shfl_xor(dist[a][b], off, 64);

        float qun[NB][4], qs[NB];
        #pragma unroll
        for (int a = 0; a < NB; ++a) {
            qs[a] = 0.0f;
            #pragma unroll
            for (int b = 0; b < 4; ++b) {
                qun[a][b] = 1.0f / (1.0f + dist[a][b] * dist[a][b]);
                qs[a] += qun[a][b];
            }
        }

        #pragma unroll
        for (int off = 8; off < 64; off <<= 1)
            #pragma unroll
            for (int a = 0; a < NB; ++a)
                qs[a] += __shfl_xor(qs[a], off, 64);

        if (f_grp == 0) {
            #pragma unroll
            for (int a = 0; a < NB; ++a) {
                float4 qv;
                qv.x = qun[a][0] / qs[a];
                qv.y = qun[a][1] / qs[a];
                qv.z = qun[a][2] / qs[a];
                qv.w = qun[a][3] / qs[a];
                *reinterpret_cast<float4*>(out + (size_t)(n0 + a) * K_DIM + k0) = qv;
            }
        }
    }
}

extern "C" void kernel_launch(void* const* d_in, const int* in_sizes, int n_in,
                              void* d_out, int out_size, void* d_ws, size_t ws_size,
                              hipStream_t stream) {
    const float* x = (const float*)d_in[0];
    const float* c = (const float*)d_in[1];
    float* out = (float*)d_out;
    float* c2  = (float*)d_ws;   // 512 KB

    transpose_c_kernel<<<dim3(131072 / 256), dim3(256), 0, stream>>>(c, c2);
    tscluster_kernel<<<dim3(2048 / NB), dim3(512), 0, stream>>>(x, c2, out);
}